// Round 9
// baseline (439.262 us; speedup 1.0000x reference)
//
#include <hip/hip_runtime.h>

// ---------------------------------------------------------------------------
// CorefPairScorer: B=4, T=4096, D=768, N=256, HID=200 (padded to 256)
// h1(i,j) = relu(A[i] + Bv[j] + (emb_i*emb_j)@W1bot + b1)
// h2 = relu(h1@W2 + b2); s = h2@W3 + b3; masked softmax rows.
// R9: latency regime fix. embJ packed into LDS once per block in A-frag
//     lane order (kills the 64-line/kt gather); h1 frag-packed for b128
//     phase-2 reads; 2-Mtile passes (acc[2][4]=32 regs, demand ~120) and
//     LDS 53248B -> target 3 blocks/CU (12 waves) for latency hiding.
// ---------------------------------------------------------------------------

#define NB 4
#define NN 256
#define DD 768
#define TT 4096
#define HP2 256          // padded hidden: 16 ntiles
#define NT2 16
#define KT1 24
#define KT2 8
#define TRI 136
#define ABS 512          // AB row stride (bf16): [A(224)@0 | B(224)@256]

typedef __attribute__((ext_vector_type(8))) short short8;
typedef __attribute__((ext_vector_type(4))) float f32x4;

union FragU { uint4 u; short8 s; };

__device__ __forceinline__ float bf2f(unsigned short x) {
    return __uint_as_float(((unsigned int)x) << 16);
}
__device__ __forceinline__ unsigned short f2bf(float f) {
    unsigned int u = __float_as_uint(f);
    u += 0x7fffu + ((u >> 16) & 1u);   // RNE
    return (unsigned short)(u >> 16);
}
__device__ __forceinline__ float blo(unsigned int v) { return __uint_as_float(v << 16); }
__device__ __forceinline__ float bhi(unsigned int v) { return __uint_as_float(v & 0xffff0000u); }
__device__ __forceinline__ unsigned int mulpack(unsigned int a, float bl, float bh) {
    unsigned int m0 = __float_as_uint(blo(a) * bl);
    unsigned int m1 = __float_as_uint(bhi(a) * bh);
    return __builtin_amdgcn_perm(m1, m0, 0x07060302u);
}

// ---------------------------------------------------------------------------
// K0: prep. Blocks 0..23: w1n. 24..47: w1s (16 ntiles). 48..55: w2s.
//     Blocks 56..1079: gather emb + fp32->bf16. LDS-tiled transpose for W.
// ---------------------------------------------------------------------------
__global__ __launch_bounds__(256) void prep_all(
    const float* __restrict__ W1, const float* __restrict__ W2,
    const float* __restrict__ ee, const int* __restrict__ eidx,
    unsigned short* __restrict__ w1n,
    unsigned short* __restrict__ w1s,
    unsigned short* __restrict__ w2s,
    unsigned short* __restrict__ emb) {
    int bx = blockIdx.x, tid = threadIdx.x;
    if (bx >= 56) {                 // gather + cast
        int g = bx - 56;
        int b = g >> 8, n = g & 255;
        int t = eidx[b * NN + n];
        const float* src = ee + ((size_t)b * TT + t) * DD;
        unsigned short* dst = emb + ((size_t)b * NN + n) * DD;
        for (int e = tid; e < DD; e += 256) dst[e] = f2bf(src[e]);
        return;
    }
    __shared__ unsigned short plds[32 * 452];   // 28928 B
    if (bx < 24) {                  // w1n: kt tile of [W1top | W1mid], 448 cols
        int kt = bx;
        for (int idx = tid; idx < 32 * 448; idx += 256) {
            int r = idx / 448, cc = idx - r * 448;
            float v;
            if (cc < 224) v = (cc < 200) ? W1[(size_t)(kt * 32 + r) * 200 + cc] : 0.f;
            else { int n = cc - 224; v = (n < 200) ? W1[(size_t)(768 + kt * 32 + r) * 200 + n] : 0.f; }
            plds[r * 452 + cc] = f2bf(v);
        }
        __syncthreads();
        for (int o = tid; o < 28 * 512; o += 256) {
            int nt = o >> 9, lane = (o >> 3) & 63, j = o & 7;
            int kl = ((lane >> 4) << 3) + j, n = nt * 16 + (lane & 15);
            w1n[(size_t)kt * 14336 + o] = plds[kl * 452 + n];
        }
    } else if (bx < 48) {           // w1s: W1bot kt tile, 256 cols (200 real)
        int kt = bx - 24;
        for (int idx = tid; idx < 32 * 256; idx += 256) {
            int r = idx >> 8, cc = idx & 255;
            float v = (cc < 200) ? W1[(size_t)(1536 + kt * 32 + r) * 200 + cc] : 0.f;
            plds[r * 260 + cc] = f2bf(v);
        }
        __syncthreads();
        for (int o = tid; o < 16 * 512; o += 256) {
            int nt = o >> 9, lane = (o >> 3) & 63, j = o & 7;
            int kl = ((lane >> 4) << 3) + j, n = nt * 16 + (lane & 15);
            w1s[(size_t)kt * 8192 + o] = plds[kl * 260 + n];
        }
    } else {                        // w2s: W2 kk tile (k<200 real), 256 cols
        int kk = bx - 48;
        for (int idx = tid; idx < 32 * 256; idx += 256) {
            int r = idx >> 8, cc = idx & 255;
            int k = kk * 32 + r;
            float v = (k < 200 && cc < 200) ? W2[(size_t)k * 200 + cc] : 0.f;
            plds[r * 260 + cc] = f2bf(v);
        }
        __syncthreads();
        for (int o = tid; o < 16 * 512; o += 256) {
            int nt = o >> 9, lane = (o >> 3) & 63, j = o & 7;
            int kl = ((lane >> 4) << 3) + j, n = nt * 16 + (lane & 15);
            w2s[(size_t)kk * 8192 + o] = plds[kl * 260 + n];
        }
    }
}

// ---------------------------------------------------------------------------
// K2: AB = emb(1024x768) @ [W1top|W1mid](768x448), bf16 MFMA, bf16 out.
//     Output cols: A -> 0..223, B -> 256..479 (pads unwritten).
// ---------------------------------------------------------------------------
__global__ __launch_bounds__(256)
void node_mfma(const unsigned short* __restrict__ emb,
               const unsigned short* __restrict__ w1n,
               unsigned short* __restrict__ AB) {
    int tid = threadIdx.x, lane = tid & 63, w = tid >> 6;
    int q = lane >> 4, c = lane & 15;
    int mt = w >> 1;
    int ng = ((blockIdx.x & 1) << 1) | (w & 1);
    int m0 = (blockIdx.x >> 1) * 32 + mt * 16;
    const uint4* ga = (const uint4*)emb + (size_t)(m0 + c) * 96;
    const uint4* gb = (const uint4*)w1n;

    f32x4 acc[7];
#pragma unroll
    for (int n = 0; n < 7; ++n) acc[n] = (f32x4){0.f, 0.f, 0.f, 0.f};

    for (int kt = 0; kt < KT1; ++kt) {
        FragU a; a.u = ga[kt * 4 + q];
#pragma unroll
        for (int n = 0; n < 7; ++n) {
            FragU bb; bb.u = gb[((kt * 28 + ng * 7 + n) << 6) + lane];
            acc[n] = __builtin_amdgcn_mfma_f32_16x16x32_bf16(a.s, bb.s, acc[n], 0, 0, 0);
        }
    }
#pragma unroll
    for (int n = 0; n < 7; ++n) {
        int col = (ng * 7 + n) * 16 + c;
        int oc = (col < 224) ? col : col + 32;
#pragma unroll
        for (int rr = 0; rr < 4; ++rr)
            AB[(size_t)(m0 + q * 4 + rr) * ABS + oc] = f2bf(acc[n][rr]);
    }
}

// ---------------------------------------------------------------------------
// K3: fused pair MLP per 16x16 (i,j) tile. 256 threads = 4 waves.
//   Wave = n-group ng (ntiles ng*4..+3, disjoint W loads). 8 passes of
//   2 Mtiles. embJ LDS-packed in A-frag order (staged once); h1 frag-packed.
// ---------------------------------------------------------------------------
__global__ __launch_bounds__(256)
void pair_mlp(
    const unsigned short* __restrict__ emb,
    const unsigned short* __restrict__ w1s,
    const unsigned short* __restrict__ w2s,
    const unsigned short* __restrict__ AB,
    const float* __restrict__ b1, const float* __restrict__ b2,
    const float* __restrict__ W3, const float* __restrict__ b3,
    float* __restrict__ S) {
    int z = blockIdx.x;
    int b = z / TRI;
    int r = z % TRI;
    int ti = (int)((sqrtf(8.f * (float)r + 1.f) - 1.f) * 0.5f);
    while ((ti + 1) * (ti + 2) / 2 <= r) ++ti;
    while (ti * (ti + 1) / 2 > r) --ti;
    int tj = r - ti * (ti + 1) / 2;
    int i0 = ti << 4, j0 = tj << 4;

    int tid = threadIdx.x;
    int lane = tid & 63;
    int ng = tid >> 6;                // wave = n-group 0..3
    int q = lane >> 4, c = lane & 15;

    __shared__ unsigned short smJ[24 * 1024];   // 24576 B: embJ A-frag packed
    __shared__ unsigned short smH[2 * 4096];    // 16384 B: h1 frag-packed, 2 Mt
    __shared__ unsigned short Bv[16 * HP2];     //  8192 B: Bv[j] + b1 (bf16)
    __shared__ float sred[4][256];              //  4096 B

    // ---- stage embJ packed: smJ[(kt*4+q)*16+c] (16B) = embJ[row c][kt,q] ----
    {
        const uint4* gJ = (const uint4*)(emb + ((size_t)b * NN + j0) * DD);
        uint4* sj = (uint4*)smJ;
#pragma unroll
        for (int e = 0; e < 6; ++e) {
            int idx = tid + 256 * e;            // 0..1535
            int kt = idx >> 6, rem = idx & 63;
            int qq = rem >> 4, cc = rem & 15;
            sj[idx] = gJ[cc * 96 + kt * 4 + qq];
        }
        // Bv: one h-col per thread per m
        for (int m = 0; m < 16; ++m) {
            float bv = (tid < 224) ? bf2f(AB[(size_t)(b * NN + j0 + m) * ABS + 256 + tid]) : 0.f;
            bv += (tid < 200) ? b1[tid] : 0.f;
            Bv[m * HP2 + tid] = f2bf(bv);
        }
    }
    __syncthreads();

    const uint4* w1f = (const uint4*)w1s;
    const uint4* w2f = (const uint4*)w2s;
    const uint4* gI  = (const uint4*)(emb + ((size_t)b * NN + i0) * DD);
    const uint4* sj  = (const uint4*)smJ;

    for (int pass = 0; pass < 8; ++pass) {
        // ---- phase 1: acc[2][4] over K=768 ----
        f32x4 acc[2][4];
#pragma unroll
        for (int t = 0; t < 2; ++t)
#pragma unroll
            for (int n = 0; n < 4; ++n)
                acc[t][n] = (f32x4){0.f, 0.f, 0.f, 0.f};

        for (int kt = 0; kt < KT1; ++kt) {
            uint4 bfr[4];
#pragma unroll
            for (int n = 0; n < 4; ++n)
                bfr[n] = w1f[(kt * NT2 + ng * 4 + n) * 64 + lane];
            uint4 ej = sj[(kt << 6) + (q << 4) + c];    // contiguous b128
            float exl = blo(ej.x), exh = bhi(ej.x);
            float eyl = blo(ej.y), eyh = bhi(ej.y);
            float ezl = blo(ej.z), ezh = bhi(ej.z);
            float ewl = blo(ej.w), ewh = bhi(ej.w);
#pragma unroll
            for (int t = 0; t < 2; ++t) {
                int tg = (pass << 1) + t;               // i-row Mtile
                uint4 ei = gI[tg * 96 + kt * 4 + q];    // quad-broadcast (L1)
                FragU a;
                a.u.x = mulpack(ei.x, exl, exh);
                a.u.y = mulpack(ei.y, eyl, eyh);
                a.u.z = mulpack(ei.z, ezl, ezh);
                a.u.w = mulpack(ei.w, ewl, ewh);
#pragma unroll
                for (int n = 0; n < 4; ++n) {
                    FragU bb; bb.u = bfr[n];
                    acc[t][n] = __builtin_amdgcn_mfma_f32_16x16x32_bf16(a.s, bb.s, acc[t][n], 0, 0, 0);
                }
            }
        }

        // ---- epilogue: h1 = relu(acc + Ai + Bv) -> smH frag-packed bf16 ----
        __syncthreads();   // prev pass's phase-2 readers done
#pragma unroll
        for (int t = 0; t < 2; ++t) {
            int tg = (pass << 1) + t;
#pragma unroll
            for (int n = 0; n < 4; ++n) {
                int h = ((ng * 4 + n) << 4) + c;
                float aI = (h < 224) ? bf2f(AB[(size_t)(b * NN + i0 + tg) * ABS + h]) : 0.f;
                int kk2 = h >> 5, q2 = (h >> 3) & 3, j2 = h & 7;
                int fb = (t << 12) + (((kk2 << 2) + q2) << 7) + j2;
#pragma unroll
                for (int rr = 0; rr < 4; ++rr) {
                    float v = acc[t][n][rr] + aI + bf2f(Bv[(q * 4 + rr) * HP2 + h]);
                    v = fmaxf(v, 0.f);
                    smH[fb + ((q * 4 + rr) << 3)] = f2bf(v);
                }
            }
        }
        __syncthreads();

        // ---- phase 2: acc2[2][4] over K=256 from packed smH ----
        f32x4 acc2[2][4];
#pragma unroll
        for (int t = 0; t < 2; ++t)
#pragma unroll
            for (int n = 0; n < 4; ++n)
                acc2[t][n] = (f32x4){0.f, 0.f, 0.f, 0.f};

        for (int kk = 0; kk < KT2; ++kk) {
            uint4 bfr2[4];
#pragma unroll
            for (int n = 0; n < 4; ++n)
                bfr2[n] = w2f[(kk * NT2 + ng * 4 + n) * 64 + lane];
#pragma unroll
            for (int t = 0; t < 2; ++t) {
                FragU a2;
                a2.u = *(const uint4*)(&smH[(t << 12) + (((kk << 2) + q) << 7) + (c << 3)]);
#pragma unroll
                for (int n = 0; n < 4; ++n) {
                    FragU bb; bb.u = bfr2[n];
                    acc2[t][n] = __builtin_amdgcn_mfma_f32_16x16x32_bf16(a2.s, bb.s, acc2[t][n], 0, 0, 0);
                }
            }
        }

        // ---- phase 3: s = relu(h2 + b2) . W3, reduce wave cols via shfl ----
#pragma unroll
        for (int t = 0; t < 2; ++t) {
#pragma unroll
            for (int rr = 0; rr < 4; ++rr) {
                float part = 0.f;
#pragma unroll
                for (int n = 0; n < 4; ++n) {
                    int h = ((ng * 4 + n) << 4) + c;
                    float b2v = (h < 200) ? b2[h] : 0.f;
                    float w3v = (h < 200) ? W3[h] : 0.f;
                    float hv = fmaxf(acc2[t][n][rr] + b2v, 0.f);
                    part += hv * w3v;
                }
                part += __shfl_xor(part, 1);
                part += __shfl_xor(part, 2);
                part += __shfl_xor(part, 4);
                part += __shfl_xor(part, 8);
                if (c == 0) {
                    int p = (((pass << 1) + t) << 4) + q * 4 + rr;
                    sred[ng][p] = part;
                }
            }
        }
    }
    __syncthreads();
    {   // final: S[b][i0+ii][j0+jj]
        int ii = tid >> 4, jj = tid & 15;
        float s = sred[0][tid] + sred[1][tid] + sred[2][tid] + sred[3][tid] + b3[0];
        S[((size_t)b * NN + i0 + ii) * NN + j0 + jj] = s;
    }
}

// ---------------------------------------------------------------------------
// K4: masked softmax per row; diag logit = 0; invalid -> -1000
// ---------------------------------------------------------------------------
__global__ __launch_bounds__(256) void softmax_rows(const float* __restrict__ S,
                                                    float* __restrict__ out) {
    int b = blockIdx.x >> 8, i = blockIdx.x & 255;
    int j = threadIdx.x;
    int lane = j & 63, w = j >> 6;
    __shared__ float red[16];
    float x = (j < i) ? S[((size_t)b * NN + i) * NN + j] : ((j == i) ? 0.f : -1e30f);
    float m = x;
#pragma unroll
    for (int off = 32; off; off >>= 1) m = fmaxf(m, __shfl_xor(m, off));
    if (lane == 0) red[w] = m;
    __syncthreads();
    float mx = fmaxf(fmaxf(red[0], red[1]), fmaxf(red[2], red[3]));
    float e = (j <= i) ? __expf(x - mx) : 0.f;
    float s = e;
#pragma unroll
    for (int off = 32; off; off >>= 1) s += __shfl_xor(s, off);
    if (lane == 0) red[8 + w] = s;
    __syncthreads();
    float sum = red[8] + red[9] + red[10] + red[11];
    out[((size_t)b * NN + i) * NN + j] = (j <= i) ? (e / sum) : -1000.0f;
}

// ---------------------------------------------------------------------------
extern "C" void kernel_launch(void* const* d_in, const int* in_sizes, int n_in,
                              void* d_out, int out_size, void* d_ws, size_t ws_size,
                              hipStream_t stream) {
    const float* ee  = (const float*)d_in[0];
    const int*   eidx = (const int*)d_in[1];
    const float* W1  = (const float*)d_in[2];
    const float* b1  = (const float*)d_in[3];
    const float* W2  = (const float*)d_in[4];
    const float* b2  = (const float*)d_in[5];
    const float* W3  = (const float*)d_in[6];
    const float* b3  = (const float*)d_in[7];
    float* out = (float*)d_out;

    char* p = (char*)d_ws;
    unsigned short* emb = (unsigned short*)p; p += (size_t)NB * NN * DD * 2;       // 1.5 MB
    unsigned short* w1s = (unsigned short*)p; p += (size_t)KT1 * 8192 * 2;         // 384 KB
    unsigned short* w2s = (unsigned short*)p; p += (size_t)KT2 * 8192 * 2;         // 128 KB
    unsigned short* AB  = (unsigned short*)p; p += (size_t)NB * NN * ABS * 2;      // 1 MB
    // w1n (672 KB, used only prep->node_mfma) aliases S (1 MB, used pair_mlp->softmax)
    unsigned short* w1n = (unsigned short*)p;
    float* S = (float*)p;  p += (size_t)NB * NN * NN * 4;                           // 1 MB

    prep_all<<<1080, 256, 0, stream>>>(W1, W2, ee, eidx, w1n, w1s, w2s, emb);
    node_mfma<<<64, 256, 0, stream>>>(emb, w1n, AB);
    pair_mlp<<<NB * TRI, 256, 0, stream>>>(emb, w1s, w2s, AB, b1, b2, W3, b3, S);
    softmax_rows<<<NB * NN, 256, 0, stream>>>(S, out);
}